// Round 5
// baseline (579.389 us; speedup 1.0000x reference)
//
#include <hip/hip_runtime.h>

typedef unsigned short u16;
typedef __attribute__((ext_vector_type(8))) short bf16x8;
typedef __attribute__((ext_vector_type(4))) float f32x4;

__device__ __forceinline__ float bf2f(u16 u) { return __uint_as_float(((unsigned)u) << 16); }
__device__ __forceinline__ u16 f2bf(float f) {
    unsigned u = __float_as_uint(f);
    return (u16)((u + 0x7FFFu + ((u >> 16) & 1u)) >> 16);
}

// fast GELU (tanh form): v * sigmoid(1.5957691*v + 0.07135481*v^3)
__device__ __forceinline__ float gelu_fast(float v) {
    float u = v * (1.5957691216057308f + 0.07135481282700722f * v * v);
    return v * (1.f / (1.f + __expf(-u)));
}

// async global->LDS, 16 B per lane. LDS dest = wave-uniform base + lane*16.
__device__ __forceinline__ void load_lds16(const u16* g, u16* l) {
    __builtin_amdgcn_global_load_lds(
        (const __attribute__((address_space(1))) unsigned int*)g,
        (__attribute__((address_space(3))) unsigned int*)l,
        16, 0, 0);
}

// ---------------------------------------------------------------------------
// gemm_nk: barrier-free N-loop GEMM for skinny-K layers.
// out = A(Mx(NKC*256)) @ Wt(Nx(NKC*256))^T.  Block = 64 rows x NT*128 cols,
// 256 threads (4 waves; wave wq owns a 32-col slice of each 128-col tile).
// A-slab (64x256 per K-chunk, 32 KB) staged via global_load_lds, XOR-swizzled
// (chunk ^= row&7, applied on the global source).  ONE barrier per K-chunk
// (NKC==1: a single barrier per block).  W fragments are read global->reg:
// W is 0.1-0.5 MB, same addresses for every block -> L2/L1-resident.
// K-chunks ping-pong two LDS slabs (stage kc+1 issued before compute kc).
// MFMA operands swapped (W-frag as A-operand): lane holds 4 consecutive
// output cols of one row -> ushort4/float4 epilogue, no barriers.
// EPI 0: +bias, bf16   1: +bias+res(f32), f32   2: +bias+gelu, bf16   3: plain, bf16
// ---------------------------------------------------------------------------
template<int EPI, int NT, int NKC>
__global__ __launch_bounds__(256, 2) void gemm_nk(
    const u16* __restrict__ A, const u16* __restrict__ Wt,
    const float* __restrict__ bias, const float* __restrict__ res,
    void* __restrict__ outp, int N)
{
    __shared__ __align__(16) u16 As[(NKC > 1) ? 2 : 1][64 * 256];
    const int tid  = threadIdx.x;
    const int lane = tid & 63;
    const int wq   = tid >> 6;             // 0..3: col 32-slice in each tile
    const int r0   = blockIdx.x * 64;
    const int c0   = blockIdx.y * (NT * 128);
    const int lr   = lane & 15;
    const int q    = lane >> 4;            // 0..3
    const int K    = NKC * 256;

    f32x4 acc[NT][4][2];
#pragma unroll
    for (int t = 0; t < NT; ++t)
#pragma unroll
        for (int i = 0; i < 4; ++i)
#pragma unroll
            for (int j = 0; j < 2; ++j) acc[t][i][j] = (f32x4){0.f, 0.f, 0.f, 0.f};

    // staging: unit u = tid + s*256 -> LDS slot u (16B), row u>>5, global
    // chunk (u&31)^((u>>5)&7).  (s*8 doesn't touch row&7, so chunk is
    // s-invariant.)  Wave = 2 rows x 32 chunks = 2 x 512 B segments.
    const int strow  = tid >> 5;                    // 0..7
    const int schunk = (tid & 31) ^ (strow & 7);
    const u16* ag = A + (size_t)(r0 + strow) * K + schunk * 8;

    auto stage = [&](int buf, int kc) {
        const u16* src = ag + kc * 256;
        u16* dst = (u16*)As[buf] + tid * 8;
#pragma unroll
        for (int s = 0; s < 8; ++s)
            load_lds16(src + (size_t)s * 8 * K, dst + s * 2048);
    };

    stage(0, 0);
    __syncthreads();                       // slab 0 resident

    const u16* wbase = Wt + (size_t)(c0 + wq * 32 + lr) * K + q * 8;

#pragma unroll 1
    for (int kc = 0; kc < NKC; ++kc) {
        if (NKC > 1 && kc + 1 < NKC) stage((kc + 1) & 1, kc + 1);
        const u16* Ab = As[(NKC > 1) ? (kc & 1) : 0];
#pragma unroll
        for (int kk = 0; kk < 8; ++kk) {
            bf16x8 af[4];
#pragma unroll
            for (int i = 0; i < 4; ++i) {
                const int r = i * 16 + lr;
                af[i] = *(const bf16x8*)(Ab + r * 256 + (((kk * 4 + q) ^ (r & 7)) * 8));
            }
#pragma unroll
            for (int t = 0; t < NT; ++t) {
                const u16* wp = wbase + (size_t)(t * 128) * K + kc * 256 + kk * 32;
                const bf16x8 wf0 = *(const bf16x8*)(wp);
                const bf16x8 wf1 = *(const bf16x8*)(wp + (size_t)16 * K);
#pragma unroll
                for (int i = 0; i < 4; ++i) {
                    acc[t][i][0] = __builtin_amdgcn_mfma_f32_16x16x32_bf16(wf0, af[i], acc[t][i][0], 0, 0, 0);
                    acc[t][i][1] = __builtin_amdgcn_mfma_f32_16x16x32_bf16(wf1, af[i], acc[t][i][1], 0, 0, 0);
                }
            }
        }
        if (NKC > 1 && kc + 1 < NKC) __syncthreads();  // drain stage(kc+1)
    }

    // swapped-operand C/D layout: row = lr, col = q*4 + reg
#pragma unroll
    for (int t = 0; t < NT; ++t) {
#pragma unroll
        for (int j = 0; j < 2; ++j) {
            const int cb = c0 + t * 128 + wq * 32 + j * 16 + q * 4;
            float4 bv;
            if (EPI == 3) { bv.x = bv.y = bv.z = bv.w = 0.f; }
            else          { bv = *(const float4*)(bias + cb); }
#pragma unroll
            for (int i = 0; i < 4; ++i) {
                const int row = r0 + i * 16 + lr;
                float v0 = acc[t][i][j][0] + bv.x;
                float v1 = acc[t][i][j][1] + bv.y;
                float v2 = acc[t][i][j][2] + bv.z;
                float v3 = acc[t][i][j][3] + bv.w;
                if (EPI == 1) {
                    const size_t o = (size_t)row * N + cb;
                    const float4 rr = *(const float4*)(res + o);
                    float4 ov;
                    ov.x = v0 + rr.x; ov.y = v1 + rr.y; ov.z = v2 + rr.z; ov.w = v3 + rr.w;
                    *(float4*)((float*)outp + o) = ov;
                } else {
                    if (EPI == 2) {
                        v0 = gelu_fast(v0); v1 = gelu_fast(v1);
                        v2 = gelu_fast(v2); v3 = gelu_fast(v3);
                    }
                    ushort4 ov;
                    ov.x = f2bf(v0); ov.y = f2bf(v1); ov.z = f2bf(v2); ov.w = f2bf(v3);
                    *(ushort4*)((u16*)outp + (size_t)row * N + cb) = ov;
                }
            }
        }
    }
}

// ---------------------------------------------------------------------------
// LN fp32-in -> bf16-out, C=256 (wave per row, 4 rows/block)
// ---------------------------------------------------------------------------
__global__ __launch_bounds__(256) void ln_f2b_kernel(
    const float* __restrict__ x, const float* __restrict__ g,
    const float* __restrict__ be, u16* __restrict__ out)
{
    const int lane = threadIdx.x & 63;
    const int row  = blockIdx.x * 4 + (threadIdx.x >> 6);
    const float4 a = *(const float4*)(x + (size_t)row * 256 + lane * 4);
    float v[4] = {a.x, a.y, a.z, a.w};
    float s = v[0] + v[1] + v[2] + v[3];
#pragma unroll
    for (int m = 1; m < 64; m <<= 1) s += __shfl_xor(s, m);
    const float mean = s * (1.f / 256.f);
    float s2 = 0.f;
#pragma unroll
    for (int e = 0; e < 4; ++e) { float d = v[e] - mean; s2 += d * d; }
#pragma unroll
    for (int m = 1; m < 64; m <<= 1) s2 += __shfl_xor(s2, m);
    const float rstd = rsqrtf(s2 * (1.f / 256.f) + 1e-5f);
    const float4 gg = *(const float4*)(g + lane * 4);
    const float4 bb = *(const float4*)(be + lane * 4);
    ushort4 o;
    o.x = f2bf((v[0] - mean) * rstd * gg.x + bb.x);
    o.y = f2bf((v[1] - mean) * rstd * gg.y + bb.y);
    o.z = f2bf((v[2] - mean) * rstd * gg.z + bb.z);
    o.w = f2bf((v[3] - mean) * rstd * gg.w + bb.w);
    *(ushort4*)(out + (size_t)row * 256 + lane * 4) = o;
}

// ---------------------------------------------------------------------------
// LN bf16-in -> fp32-out, C=512 (wave per row, 4 rows/block)
// ---------------------------------------------------------------------------
__global__ __launch_bounds__(256) void ln_b2f_kernel(
    const u16* __restrict__ x, const float* __restrict__ g,
    const float* __restrict__ be, float* __restrict__ out)
{
    const int lane = threadIdx.x & 63;
    const int row  = blockIdx.x * 4 + (threadIdx.x >> 6);
    const u16* xr = x + (size_t)row * 512 + lane * 8;
    float v[8];
#pragma unroll
    for (int e = 0; e < 8; e += 4) {
        ushort4 a = *(const ushort4*)(xr + e);
        v[e] = bf2f(a.x); v[e+1] = bf2f(a.y); v[e+2] = bf2f(a.z); v[e+3] = bf2f(a.w);
    }
    float s = 0.f;
#pragma unroll
    for (int e = 0; e < 8; ++e) s += v[e];
#pragma unroll
    for (int m = 1; m < 64; m <<= 1) s += __shfl_xor(s, m);
    const float mean = s * (1.f / 512.f);
    float s2 = 0.f;
#pragma unroll
    for (int e = 0; e < 8; ++e) { float d = v[e] - mean; s2 += d * d; }
#pragma unroll
    for (int m = 1; m < 64; m <<= 1) s2 += __shfl_xor(s2, m);
    const float rstd = rsqrtf(s2 * (1.f / 512.f) + 1e-5f);
    float* orow = out + (size_t)row * 512 + lane * 8;
#pragma unroll
    for (int e = 0; e < 8; e += 4) {
        float4 o;
        o.x = (v[e]   - mean) * rstd * g[lane*8+e]   + be[lane*8+e];
        o.y = (v[e+1] - mean) * rstd * g[lane*8+e+1] + be[lane*8+e+1];
        o.z = (v[e+2] - mean) * rstd * g[lane*8+e+2] + be[lane*8+e+2];
        o.w = (v[e+3] - mean) * rstd * g[lane*8+e+3] + be[lane*8+e+3];
        *(float4*)(orow + e) = o;
    }
}

// ---------------------------------------------------------------------------
// NAT attention: wave per token, 8 heads x 8 lanes, HD=32 (4 dims/lane), K=7
// ---------------------------------------------------------------------------
__global__ __launch_bounds__(256) void attn_kernel(
    const u16* __restrict__ qkv, u16* __restrict__ out)
{
    const int lane  = threadIdx.x & 63;
    const int token = blockIdx.x * 4 + (threadIdx.x >> 6);
    const int b = token >> 11;
    const int l = token & 2047;
    const int h = lane >> 3;
    const int s = lane & 7;
    const int off = h * 32 + s * 4;

    ushort4 q4 = *(const ushort4*)(qkv + (size_t)token * 768 + off);
    const float scale = 0.17677669529663687f;  // 32^-0.5
    float q0 = bf2f(q4.x), q1 = bf2f(q4.y), q2 = bf2f(q4.z), q3 = bf2f(q4.w);

    int start = l - 3;
    start = start < 0 ? 0 : (start > 2041 ? 2041 : start);
    const u16* kbase = qkv + ((size_t)(b << 11) + start) * 768 + 256 + off;

    float sc[7], vv[7][4];
#pragma unroll
    for (int j = 0; j < 7; ++j) {
        const u16* kp = kbase + (size_t)j * 768;
        ushort4 k4 = *(const ushort4*)kp;
        ushort4 v4 = *(const ushort4*)(kp + 256);
        float d = q0 * bf2f(k4.x) + q1 * bf2f(k4.y) + q2 * bf2f(k4.z) + q3 * bf2f(k4.w);
        d += __shfl_xor(d, 1); d += __shfl_xor(d, 2); d += __shfl_xor(d, 4);
        sc[j] = d * scale;
        vv[j][0] = bf2f(v4.x); vv[j][1] = bf2f(v4.y); vv[j][2] = bf2f(v4.z); vv[j][3] = bf2f(v4.w);
    }
    float mx = sc[0];
#pragma unroll
    for (int j = 1; j < 7; ++j) mx = fmaxf(mx, sc[j]);
    float p[7], sum = 0.f;
#pragma unroll
    for (int j = 0; j < 7; ++j) { p[j] = __expf(sc[j] - mx); sum += p[j]; }
    const float inv = 1.f / sum;
    float o0 = 0, o1 = 0, o2 = 0, o3 = 0;
#pragma unroll
    for (int j = 0; j < 7; ++j) {
        o0 += p[j] * vv[j][0]; o1 += p[j] * vv[j][1];
        o2 += p[j] * vv[j][2]; o3 += p[j] * vv[j][3];
    }
    ushort4 o;
    o.x = f2bf(o0 * inv); o.y = f2bf(o1 * inv); o.z = f2bf(o2 * inv); o.w = f2bf(o3 * inv);
    *(ushort4*)(out + (size_t)token * 256 + off) = o;
}

// ---------------------------------------------------------------------------
// weight prep: fp32 [d][K][N] -> bf16 [d][N][K], 32x32 LDS tile transpose
// grid (N/32, K/32, d), 256 threads
// ---------------------------------------------------------------------------
__global__ __launch_bounds__(256) void transpose_kernel(
    const float* __restrict__ in, u16* __restrict__ out, int K, int N)
{
    __shared__ float t[32][33];
    const int n0 = blockIdx.x * 32;
    const int k0 = blockIdx.y * 32;
    const int d  = blockIdx.z;
    const int tr = threadIdx.x >> 3;         // 0..31
    const int tc = (threadIdx.x & 7) * 4;    // 0,4,...,28
    const float4 a = *(const float4*)(in + ((size_t)d * K + k0 + tr) * N + n0 + tc);
    t[tc + 0][tr] = a.x; t[tc + 1][tr] = a.y; t[tc + 2][tr] = a.z; t[tc + 3][tr] = a.w;
    __syncthreads();
    ushort4 o;
    o.x = f2bf(t[tr][tc + 0]); o.y = f2bf(t[tr][tc + 1]);
    o.z = f2bf(t[tr][tc + 2]); o.w = f2bf(t[tr][tc + 3]);
    *(ushort4*)(out + ((size_t)d * N + n0 + tr) * K + k0 + tc) = o;
}

// conv_w fp32 (512,256,3) [co][ci][t] -> bf16 (512,768) [co][t*256+ci]
__global__ void convw_kernel(const float* __restrict__ in, u16* __restrict__ out)
{
    int idx = blockIdx.x * 256 + threadIdx.x;
    int r  = idx % 768;
    int co = idx / 768;
    int t  = r / 256;
    int ci = r % 256;
    out[idx] = f2bf(in[(size_t)co * 768 + (size_t)ci * 3 + t]);
}

// im2col chunk: x2[rl][t*256+ci] = bf16(x[b, 2*lo+t-1, ci]), fp32 source
__global__ __launch_bounds__(256) void im2col_kernel(
    const float* __restrict__ x, u16* __restrict__ x2, int r0)
{
    int idx = blockIdx.x * 256 + threadIdx.x;
    int c4  = idx & 63;
    int t   = (idx >> 6) % 3;
    int rl  = idx / 192;
    int row = r0 + rl;
    int b   = row >> 10;
    int lo  = row & 1023;
    int l   = 2 * lo + t - 1;
    ushort4 o = {0, 0, 0, 0};
    if (l >= 0 && l < 2048) {
        float4 val = *(const float4*)(x + ((size_t)(b << 11) + l) * 256 + c4 * 4);
        o.x = f2bf(val.x); o.y = f2bf(val.y); o.z = f2bf(val.z); o.w = f2bf(val.w);
    }
    *(ushort4*)(x2 + (size_t)rl * 768 + t * 256 + c4 * 4) = o;
}

// ---------------------------------------------------------------------------
extern "C" void kernel_launch(void* const* d_in, const int* in_sizes, int n_in,
                              void* d_out, int out_size, void* d_ws, size_t ws_size,
                              hipStream_t stream)
{
    const float* x_in   = (const float*)d_in[0];
    const float* ln1_g  = (const float*)d_in[1];
    const float* ln1_b  = (const float*)d_in[2];
    const float* qkv_w  = (const float*)d_in[3];
    const float* qkv_b  = (const float*)d_in[4];
    const float* proj_w = (const float*)d_in[5];
    const float* proj_b = (const float*)d_in[6];
    const float* ln2_g  = (const float*)d_in[7];
    const float* ln2_b  = (const float*)d_in[8];
    const float* fc1_w  = (const float*)d_in[9];
    const float* fc1_b  = (const float*)d_in[10];
    const float* fc2_w  = (const float*)d_in[11];
    const float* fc2_b  = (const float*)d_in[12];
    const float* conv_w = (const float*)d_in[13];
    const float* dn_g   = (const float*)d_in[14];
    const float* dn_b   = (const float*)d_in[15];

    // d_out fp32: y [0, 8388608), x [8388608, 16777216). Running x in-place;
    // bf16 LN scratch xn borrows the y region (last written).
    float* xbuf = (float*)d_out + 8388608;
    u16*   xn   = (u16*)d_out;

    char* ws = (char*)d_ws;
    const size_t MB = 1024ull * 1024;
    u16* qkv_wt  = (u16*)ws;                  // 2x768x256  bf16 (0.75 MB)
    u16* proj_wt = qkv_wt  + 2 * 768 * 256;   // 2x256x256
    u16* fc1_wt  = proj_wt + 2 * 256 * 256;   // 2x1024x256
    u16* fc2_wt  = fc1_wt  + 2 * 1024 * 256;  // 2x256x1024
    u16* conv_wt = fc2_wt  + 2 * 256 * 1024;  // 512x768
    u16* S       = (u16*)(ws + 4 * MB);       // chunk scratch

    const size_t R = ws_size > 4 * MB ? ws_size - 4 * MB : 0;
    int nb = 16;    while (nb > 1 && (size_t)nb * 4 * MB > R) nb >>= 1;     // qkv chunk (batches)
    int Mf = 32768; while (Mf > 2048 && (size_t)Mf * 2048 > R) Mf >>= 1;    // mlp rows
    int Mc = 16384; while (Mc > 2048 && (size_t)Mc * 2560 > R) Mc >>= 1;    // conv rows

    transpose_kernel<<<dim3(768 / 32, 256 / 32, 2), 256, 0, stream>>>(qkv_w,  qkv_wt,  256, 768);
    transpose_kernel<<<dim3(256 / 32, 256 / 32, 2), 256, 0, stream>>>(proj_w, proj_wt, 256, 256);
    transpose_kernel<<<dim3(1024 / 32, 256 / 32, 2), 256, 0, stream>>>(fc1_w, fc1_wt, 256, 1024);
    transpose_kernel<<<dim3(256 / 32, 1024 / 32, 2), 256, 0, stream>>>(fc2_w, fc2_wt, 1024, 256);
    convw_kernel<<<(512 * 768) / 256, 256, 0, stream>>>(conv_w, conv_wt);

    for (int layer = 0; layer < 2; ++layer) {
        const float* l1g = ln1_g + layer * 256;
        const float* l1b = ln1_b + layer * 256;
        const float* l2g = ln2_g + layer * 256;
        const float* l2b = ln2_b + layer * 256;
        const u16*   qwt = qkv_wt  + (size_t)layer * 768 * 256;
        const float* qb  = qkv_b   + layer * 768;
        const u16*   pwt = proj_wt + (size_t)layer * 256 * 256;
        const float* pb  = proj_b  + layer * 256;
        const u16*   f1w = fc1_wt  + (size_t)layer * 1024 * 256;
        const float* f1b = fc1_b   + layer * 1024;
        const u16*   f2w = fc2_wt  + (size_t)layer * 256 * 1024;
        const float* f2b = fc2_b   + layer * 256;

        // layer 0 reads the original input directly (skips the 32 MB D2D copy)
        const float* xsrc = (layer == 0) ? x_in : xbuf;

        ln_f2b_kernel<<<8192, 256, 0, stream>>>(xsrc, l1g, l1b, xn);
        {
            const int Mg = nb * 2048;
            u16* qkvc  = S;
            u16* atnoc = S + (size_t)Mg * 768;
            for (int g = 0; g < 16 / nb; ++g) {
                const size_t t0 = (size_t)g * Mg;
                // qkv: N=768, K=256, NT=3 -> grid (Mg/64, 2)
                gemm_nk<0, 3, 1><<<dim3(Mg / 64, 2), 256, 0, stream>>>(
                    xn + t0 * 256, qwt, qb, nullptr, qkvc, 768);
                attn_kernel<<<Mg / 4, 256, 0, stream>>>(qkvc, atnoc);
                // proj: N=256, K=256, NT=2 -> grid (Mg/64, 1)
                gemm_nk<1, 2, 1><<<dim3(Mg / 64, 1), 256, 0, stream>>>(
                    atnoc, pwt, pb, xsrc + t0 * 256, xbuf + t0 * 256, 256);
            }
        }
        ln_f2b_kernel<<<8192, 256, 0, stream>>>(xbuf, l2g, l2b, xn);
        {
            u16* hbuf = S;
            for (int qq = 0; qq < 32768 / Mf; ++qq) {
                const size_t r0 = (size_t)qq * Mf;
                // fc1: N=1024, K=256, NT=4 -> grid (Mf/64, 2)
                gemm_nk<2, 4, 1><<<dim3(Mf / 64, 2), 256, 0, stream>>>(
                    xn + r0 * 256, f1w, f1b, nullptr, hbuf, 1024);
                // fc2: N=256, K=1024 (NKC=4), NT=2 -> grid (Mf/64, 1)
                gemm_nk<1, 2, 4><<<dim3(Mf / 64, 1), 256, 0, stream>>>(
                    hbuf, f2w, f2b, xbuf + r0 * 256, xbuf + r0 * 256, 256);
            }
        }
    }

    // downsample conv (im2col GEMM) + final LN -> fp32 y, chunked
    {
        u16* x2c = S;
        u16* ycc = S + (size_t)Mc * 768;
        for (int c = 0; c < 16384 / Mc; ++c) {
            const int r0 = c * Mc;
            im2col_kernel<<<3 * Mc / 4, 256, 0, stream>>>(xbuf, x2c, r0);
            // conv: N=512, K=768 (NKC=3), NT=2 -> grid (Mc/64, 2)
            gemm_nk<3, 2, 3><<<dim3(Mc / 64, 2), 256, 0, stream>>>(
                x2c, conv_wt, nullptr, nullptr, ycc, 512);
            ln_b2f_kernel<<<Mc / 4, 256, 0, stream>>>(
                ycc, dn_g, dn_b, (float*)d_out + (size_t)r0 * 512);
        }
    }
    // x output already in place (xbuf aliases d_out's x-region)
}

// Round 6
// 499.491 us; speedup vs baseline: 1.1600x; 1.1600x over previous
//
#include <hip/hip_runtime.h>

typedef unsigned short u16;
typedef __attribute__((ext_vector_type(8))) short bf16x8;
typedef __attribute__((ext_vector_type(4))) float f32x4;

__device__ __forceinline__ float bf2f(u16 u) { return __uint_as_float(((unsigned)u) << 16); }
__device__ __forceinline__ u16 f2bf(float f) {
    unsigned u = __float_as_uint(f);
    return (u16)((u + 0x7FFFu + ((u >> 16) & 1u)) >> 16);
}

// fast GELU (tanh form): v * sigmoid(1.5957691*v + 0.07135481*v^3)
__device__ __forceinline__ float gelu_fast(float v) {
    float u = v * (1.5957691216057308f + 0.07135481282700722f * v * v);
    return v * (1.f / (1.f + __expf(-u)));
}

// async global->LDS, 16 B per lane. LDS dest = wave-uniform base + lane*16.
__device__ __forceinline__ void load_lds16(const u16* g, u16* l) {
    __builtin_amdgcn_global_load_lds(
        (const __attribute__((address_space(1))) unsigned int*)g,
        (__attribute__((address_space(3))) unsigned int*)l,
        16, 0, 0);
}

// ---------------------------------------------------------------------------
// GEMM, T4 counted-vmcnt pipeline: BK=32, TRIPLE-buffered LDS (48 KB),
// 2-deep prefetch.  Per K-step: s_waitcnt vmcnt(4) (waits own stage(t) only,
// stage(t+1)'s 4 loads stay in flight ACROSS the barrier) -> raw s_barrier ->
// issue stage(t+2) -> compute(t).  vmcnt never drains to 0 mid-loop (m218).
// WAR-safe: stage(t+2) overwrites buf[(t-1)%3], whose readers finished
// before the barrier at iter t.
// out = A(MxK) @ Wt(NxK)^T, bf16 in, fp32 acc.  K % 32 == 0, K >= 64.
// LDS slot swizzle: row r, k-chunk q at slot q ^ ((r>>1)&3) (involution,
// applied on the per-lane GLOBAL source; LDS dest stays lane-linear).
// MFMA operands SWAPPED (W-frag as A-operand): lane holds 4 consecutive
// output cols of one row -> ushort4/float4 epilogue, i-outer row-grouped.
// EPI 0: +bias, bf16   1: +bias+res(f32), f32   2: +bias+gelu, bf16   3: plain, bf16
// ---------------------------------------------------------------------------
template<int EPI>
__global__ __launch_bounds__(256) void gemm_kernel(
    const u16* __restrict__ A, const u16* __restrict__ Wt,
    const float* __restrict__ bias, const float* __restrict__ res,
    void* __restrict__ outp, int M, int N, int K)
{
    __shared__ __align__(16) u16 As[3][128 * 32];   // 3 x 8 KB
    __shared__ __align__(16) u16 Bs[3][128 * 32];   // 3 x 8 KB
    const int tid  = threadIdx.x;
    const int lane = tid & 63;
    const int wave = tid >> 6;
    const int row0 = blockIdx.x * 128;
    const int col0 = blockIdx.y * 128;
    const int wr = (wave >> 1) * 64;
    const int wc = (wave & 1) * 64;
    const int lr = lane & 15;
    const int q  = lane >> 4;            // 0..3

    f32x4 acc[4][4];
#pragma unroll
    for (int i = 0; i < 4; ++i)
#pragma unroll
        for (int j = 0; j < 4; ++j) acc[i][j] = (f32x4){0.f, 0.f, 0.f, 0.f};

    // staging: unit u (0..511) -> LDS 16B-slot u, row u>>2, global chunk
    // (u&3) ^ ((u>>3)&3).  2 units/thread/matrix.
    const int u0 = tid, u1 = tid + 256;
    const int r_u0 = u0 >> 2, r_u1 = u1 >> 2;
    const int c_u0 = (u0 & 3) ^ ((u0 >> 3) & 3);
    const int c_u1 = (u1 & 3) ^ ((u1 >> 3) & 3);
    const u16* agA0 = A  + (size_t)(row0 + r_u0) * K + c_u0 * 8;
    const u16* agA1 = A  + (size_t)(row0 + r_u1) * K + c_u1 * 8;
    const u16* bgB0 = Wt + (size_t)(col0 + r_u0) * K + c_u0 * 8;
    const u16* bgB1 = Wt + (size_t)(col0 + r_u1) * K + c_u1 * 8;

    const int nt = K >> 5;

    auto stage = [&](int b, int t) {
        const int k0 = t << 5;
        load_lds16(agA0 + k0, As[b] + u0 * 8);
        load_lds16(agA1 + k0, As[b] + u1 * 8);
        load_lds16(bgB0 + k0, Bs[b] + u0 * 8);
        load_lds16(bgB1 + k0, Bs[b] + u1 * 8);
    };

    auto compute = [&](int b) {
        const u16* Ab = As[b];
        const u16* Bb = Bs[b];
        bf16x8 af[4], bfv[4];
#pragma unroll
        for (int i = 0; i < 4; ++i) {
            const int r = wr + i * 16 + lr;
            af[i] = *(const bf16x8*)(Ab + r * 32 + ((q ^ ((r >> 1) & 3)) * 8));
        }
#pragma unroll
        for (int j = 0; j < 4; ++j) {
            const int r = wc + j * 16 + lr;
            bfv[j] = *(const bf16x8*)(Bb + r * 32 + ((q ^ ((r >> 1) & 3)) * 8));
        }
#pragma unroll
        for (int i = 0; i < 4; ++i)
#pragma unroll
            for (int j = 0; j < 4; ++j)
                acc[i][j] = __builtin_amdgcn_mfma_f32_16x16x32_bf16(bfv[j], af[i], acc[i][j], 0, 0, 0);
    };

    // prologue: 2 stages in flight (8 VMEM instrs/thread)
    stage(0, 0);
    stage(1, 1);

    int bc = 0;                            // compute buffer (t % 3)
#pragma unroll 1
    for (int t = 0; t < nt - 1; ++t) {
        // wait own stage(t) complete; stage(t+1) stays in flight
        asm volatile("s_waitcnt vmcnt(4)" ::: "memory");
        __builtin_amdgcn_s_barrier();      // all waves' stage(t) resident
        asm volatile("" ::: "memory");
        if (t + 2 < nt) {
            int bs = bc + 2; if (bs >= 3) bs -= 3;
            stage(bs, t + 2);              // overwrites buf[(t-1)%3]: safe
        }
        compute(bc);
        if (++bc == 3) bc = 0;
    }
    asm volatile("s_waitcnt vmcnt(0)" ::: "memory");
    __builtin_amdgcn_s_barrier();
    asm volatile("" ::: "memory");
    compute(bc);

    // swapped-operand C/D layout: row = lr, col = q*4 + reg
    float4 bv[4];
#pragma unroll
    for (int j = 0; j < 4; ++j) {
        if (EPI == 3) { bv[j].x = bv[j].y = bv[j].z = bv[j].w = 0.f; }
        else          { bv[j] = *(const float4*)(bias + col0 + wc + j * 16 + q * 4); }
    }
#pragma unroll
    for (int i = 0; i < 4; ++i) {
        const int row = row0 + wr + i * 16 + lr;
#pragma unroll
        for (int j = 0; j < 4; ++j) {
            const int cb = col0 + wc + j * 16 + q * 4;
            float v0 = acc[i][j][0] + bv[j].x;
            float v1 = acc[i][j][1] + bv[j].y;
            float v2 = acc[i][j][2] + bv[j].z;
            float v3 = acc[i][j][3] + bv[j].w;
            if (EPI == 1) {
                const size_t o = (size_t)row * N + cb;
                const float4 rr = *(const float4*)(res + o);
                float4 ov;
                ov.x = v0 + rr.x; ov.y = v1 + rr.y; ov.z = v2 + rr.z; ov.w = v3 + rr.w;
                *(float4*)((float*)outp + o) = ov;
            } else {
                if (EPI == 2) {
                    v0 = gelu_fast(v0); v1 = gelu_fast(v1);
                    v2 = gelu_fast(v2); v3 = gelu_fast(v3);
                }
                ushort4 ov;
                ov.x = f2bf(v0); ov.y = f2bf(v1); ov.z = f2bf(v2); ov.w = f2bf(v3);
                *(ushort4*)((u16*)outp + (size_t)row * N + cb) = ov;
            }
        }
    }
}

// ---------------------------------------------------------------------------
// LN fp32-in -> bf16-out, C=256 (wave per row, 4 rows/block)
// ---------------------------------------------------------------------------
__global__ __launch_bounds__(256) void ln_f2b_kernel(
    const float* __restrict__ x, const float* __restrict__ g,
    const float* __restrict__ be, u16* __restrict__ out)
{
    const int lane = threadIdx.x & 63;
    const int row  = blockIdx.x * 4 + (threadIdx.x >> 6);
    const float4 a = *(const float4*)(x + (size_t)row * 256 + lane * 4);
    float v[4] = {a.x, a.y, a.z, a.w};
    float s = v[0] + v[1] + v[2] + v[3];
#pragma unroll
    for (int m = 1; m < 64; m <<= 1) s += __shfl_xor(s, m);
    const float mean = s * (1.f / 256.f);
    float s2 = 0.f;
#pragma unroll
    for (int e = 0; e < 4; ++e) { float d = v[e] - mean; s2 += d * d; }
#pragma unroll
    for (int m = 1; m < 64; m <<= 1) s2 += __shfl_xor(s2, m);
    const float rstd = rsqrtf(s2 * (1.f / 256.f) + 1e-5f);
    const float4 gg = *(const float4*)(g + lane * 4);
    const float4 bb = *(const float4*)(be + lane * 4);
    ushort4 o;
    o.x = f2bf((v[0] - mean) * rstd * gg.x + bb.x);
    o.y = f2bf((v[1] - mean) * rstd * gg.y + bb.y);
    o.z = f2bf((v[2] - mean) * rstd * gg.z + bb.z);
    o.w = f2bf((v[3] - mean) * rstd * gg.w + bb.w);
    *(ushort4*)(out + (size_t)row * 256 + lane * 4) = o;
}

// ---------------------------------------------------------------------------
// LN bf16-in -> fp32-out, C=512 (wave per row, 4 rows/block)
// ---------------------------------------------------------------------------
__global__ __launch_bounds__(256) void ln_b2f_kernel(
    const u16* __restrict__ x, const float* __restrict__ g,
    const float* __restrict__ be, float* __restrict__ out)
{
    const int lane = threadIdx.x & 63;
    const int row  = blockIdx.x * 4 + (threadIdx.x >> 6);
    const u16* xr = x + (size_t)row * 512 + lane * 8;
    float v[8];
#pragma unroll
    for (int e = 0; e < 8; e += 4) {
        ushort4 a = *(const ushort4*)(xr + e);
        v[e] = bf2f(a.x); v[e+1] = bf2f(a.y); v[e+2] = bf2f(a.z); v[e+3] = bf2f(a.w);
    }
    float s = 0.f;
#pragma unroll
    for (int e = 0; e < 8; ++e) s += v[e];
#pragma unroll
    for (int m = 1; m < 64; m <<= 1) s += __shfl_xor(s, m);
    const float mean = s * (1.f / 512.f);
    float s2 = 0.f;
#pragma unroll
    for (int e = 0; e < 8; ++e) { float d = v[e] - mean; s2 += d * d; }
#pragma unroll
    for (int m = 1; m < 64; m <<= 1) s2 += __shfl_xor(s2, m);
    const float rstd = rsqrtf(s2 * (1.f / 512.f) + 1e-5f);
    float* orow = out + (size_t)row * 512 + lane * 8;
#pragma unroll
    for (int e = 0; e < 8; e += 4) {
        float4 o;
        o.x = (v[e]   - mean) * rstd * g[lane*8+e]   + be[lane*8+e];
        o.y = (v[e+1] - mean) * rstd * g[lane*8+e+1] + be[lane*8+e+1];
        o.z = (v[e+2] - mean) * rstd * g[lane*8+e+2] + be[lane*8+e+2];
        o.w = (v[e+3] - mean) * rstd * g[lane*8+e+3] + be[lane*8+e+3];
        *(float4*)(orow + e) = o;
    }
}

// ---------------------------------------------------------------------------
// NAT attention: wave per token, 8 heads x 8 lanes, HD=32 (4 dims/lane), K=7
// ---------------------------------------------------------------------------
__global__ __launch_bounds__(256) void attn_kernel(
    const u16* __restrict__ qkv, u16* __restrict__ out)
{
    const int lane  = threadIdx.x & 63;
    const int token = blockIdx.x * 4 + (threadIdx.x >> 6);
    const int b = token >> 11;
    const int l = token & 2047;
    const int h = lane >> 3;
    const int s = lane & 7;
    const int off = h * 32 + s * 4;

    ushort4 q4 = *(const ushort4*)(qkv + (size_t)token * 768 + off);
    const float scale = 0.17677669529663687f;  // 32^-0.5
    float q0 = bf2f(q4.x), q1 = bf2f(q4.y), q2 = bf2f(q4.z), q3 = bf2f(q4.w);

    int start = l - 3;
    start = start < 0 ? 0 : (start > 2041 ? 2041 : start);
    const u16* kbase = qkv + ((size_t)(b << 11) + start) * 768 + 256 + off;

    float sc[7], vv[7][4];
#pragma unroll
    for (int j = 0; j < 7; ++j) {
        const u16* kp = kbase + (size_t)j * 768;
        ushort4 k4 = *(const ushort4*)kp;
        ushort4 v4 = *(const ushort4*)(kp + 256);
        float d = q0 * bf2f(k4.x) + q1 * bf2f(k4.y) + q2 * bf2f(k4.z) + q3 * bf2f(k4.w);
        d += __shfl_xor(d, 1); d += __shfl_xor(d, 2); d += __shfl_xor(d, 4);
        sc[j] = d * scale;
        vv[j][0] = bf2f(v4.x); vv[j][1] = bf2f(v4.y); vv[j][2] = bf2f(v4.z); vv[j][3] = bf2f(v4.w);
    }
    float mx = sc[0];
#pragma unroll
    for (int j = 1; j < 7; ++j) mx = fmaxf(mx, sc[j]);
    float p[7], sum = 0.f;
#pragma unroll
    for (int j = 0; j < 7; ++j) { p[j] = __expf(sc[j] - mx); sum += p[j]; }
    const float inv = 1.f / sum;
    float o0 = 0, o1 = 0, o2 = 0, o3 = 0;
#pragma unroll
    for (int j = 0; j < 7; ++j) {
        o0 += p[j] * vv[j][0]; o1 += p[j] * vv[j][1];
        o2 += p[j] * vv[j][2]; o3 += p[j] * vv[j][3];
    }
    ushort4 o;
    o.x = f2bf(o0 * inv); o.y = f2bf(o1 * inv); o.z = f2bf(o2 * inv); o.w = f2bf(o3 * inv);
    *(ushort4*)(out + (size_t)token * 256 + off) = o;
}

// ---------------------------------------------------------------------------
// weight prep: fp32 [d][K][N] -> bf16 [d][N][K], 32x32 LDS tile transpose
// grid (N/32, K/32, d), 256 threads
// ---------------------------------------------------------------------------
__global__ __launch_bounds__(256) void transpose_kernel(
    const float* __restrict__ in, u16* __restrict__ out, int K, int N)
{
    __shared__ float t[32][33];
    const int n0 = blockIdx.x * 32;
    const int k0 = blockIdx.y * 32;
    const int d  = blockIdx.z;
    const int tr = threadIdx.x >> 3;         // 0..31
    const int tc = (threadIdx.x & 7) * 4;    // 0,4,...,28
    const float4 a = *(const float4*)(in + ((size_t)d * K + k0 + tr) * N + n0 + tc);
    t[tc + 0][tr] = a.x; t[tc + 1][tr] = a.y; t[tc + 2][tr] = a.z; t[tc + 3][tr] = a.w;
    __syncthreads();
    ushort4 o;
    o.x = f2bf(t[tr][tc + 0]); o.y = f2bf(t[tr][tc + 1]);
    o.z = f2bf(t[tr][tc + 2]); o.w = f2bf(t[tr][tc + 3]);
    *(ushort4*)(out + ((size_t)d * N + n0 + tr) * K + k0 + tc) = o;
}

// conv_w fp32 (512,256,3) [co][ci][t] -> bf16 (512,768) [co][t*256+ci]
__global__ void convw_kernel(const float* __restrict__ in, u16* __restrict__ out)
{
    int idx = blockIdx.x * 256 + threadIdx.x;
    int r  = idx % 768;
    int co = idx / 768;
    int t  = r / 256;
    int ci = r % 256;
    out[idx] = f2bf(in[(size_t)co * 768 + (size_t)ci * 3 + t]);
}

// im2col chunk: x2[rl][t*256+ci] = bf16(x[b, 2*lo+t-1, ci]), fp32 source
__global__ __launch_bounds__(256) void im2col_kernel(
    const float* __restrict__ x, u16* __restrict__ x2, int r0)
{
    int idx = blockIdx.x * 256 + threadIdx.x;
    int c4  = idx & 63;
    int t   = (idx >> 6) % 3;
    int rl  = idx / 192;
    int row = r0 + rl;
    int b   = row >> 10;
    int lo  = row & 1023;
    int l   = 2 * lo + t - 1;
    ushort4 o = {0, 0, 0, 0};
    if (l >= 0 && l < 2048) {
        float4 val = *(const float4*)(x + ((size_t)(b << 11) + l) * 256 + c4 * 4);
        o.x = f2bf(val.x); o.y = f2bf(val.y); o.z = f2bf(val.z); o.w = f2bf(val.w);
    }
    *(ushort4*)(x2 + (size_t)rl * 768 + t * 256 + c4 * 4) = o;
}

// ---------------------------------------------------------------------------
extern "C" void kernel_launch(void* const* d_in, const int* in_sizes, int n_in,
                              void* d_out, int out_size, void* d_ws, size_t ws_size,
                              hipStream_t stream)
{
    const float* x_in   = (const float*)d_in[0];
    const float* ln1_g  = (const float*)d_in[1];
    const float* ln1_b  = (const float*)d_in[2];
    const float* qkv_w  = (const float*)d_in[3];
    const float* qkv_b  = (const float*)d_in[4];
    const float* proj_w = (const float*)d_in[5];
    const float* proj_b = (const float*)d_in[6];
    const float* ln2_g  = (const float*)d_in[7];
    const float* ln2_b  = (const float*)d_in[8];
    const float* fc1_w  = (const float*)d_in[9];
    const float* fc1_b  = (const float*)d_in[10];
    const float* fc2_w  = (const float*)d_in[11];
    const float* fc2_b  = (const float*)d_in[12];
    const float* conv_w = (const float*)d_in[13];
    const float* dn_g   = (const float*)d_in[14];
    const float* dn_b   = (const float*)d_in[15];

    // d_out fp32: y [0, 8388608), x [8388608, 16777216). Running x in-place;
    // bf16 LN scratch xn borrows the y region (last written).
    float* xbuf = (float*)d_out + 8388608;
    u16*   xn   = (u16*)d_out;

    char* ws = (char*)d_ws;
    const size_t MB = 1024ull * 1024;
    u16* qkv_wt  = (u16*)ws;                  // 2x768x256  bf16 (0.75 MB)
    u16* proj_wt = qkv_wt  + 2 * 768 * 256;   // 2x256x256
    u16* fc1_wt  = proj_wt + 2 * 256 * 256;   // 2x1024x256
    u16* fc2_wt  = fc1_wt  + 2 * 1024 * 256;  // 2x256x1024
    u16* conv_wt = fc2_wt  + 2 * 256 * 1024;  // 512x768
    u16* S       = (u16*)(ws + 4 * MB);       // chunk scratch

    const size_t R = ws_size > 4 * MB ? ws_size - 4 * MB : 0;
    int nb = 16;    while (nb > 1 && (size_t)nb * 4 * MB > R) nb >>= 1;     // qkv chunk (batches)
    int Mf = 32768; while (Mf > 2048 && (size_t)Mf * 2048 > R) Mf >>= 1;    // mlp rows
    int Mc = 16384; while (Mc > 2048 && (size_t)Mc * 2560 > R) Mc >>= 1;    // conv rows

    transpose_kernel<<<dim3(768 / 32, 256 / 32, 2), 256, 0, stream>>>(qkv_w,  qkv_wt,  256, 768);
    transpose_kernel<<<dim3(256 / 32, 256 / 32, 2), 256, 0, stream>>>(proj_w, proj_wt, 256, 256);
    transpose_kernel<<<dim3(1024 / 32, 256 / 32, 2), 256, 0, stream>>>(fc1_w, fc1_wt, 256, 1024);
    transpose_kernel<<<dim3(256 / 32, 1024 / 32, 2), 256, 0, stream>>>(fc2_w, fc2_wt, 1024, 256);
    convw_kernel<<<(512 * 768) / 256, 256, 0, stream>>>(conv_w, conv_wt);

    for (int layer = 0; layer < 2; ++layer) {
        const float* l1g = ln1_g + layer * 256;
        const float* l1b = ln1_b + layer * 256;
        const float* l2g = ln2_g + layer * 256;
        const float* l2b = ln2_b + layer * 256;
        const u16*   qwt = qkv_wt  + (size_t)layer * 768 * 256;
        const float* qb  = qkv_b   + layer * 768;
        const u16*   pwt = proj_wt + (size_t)layer * 256 * 256;
        const float* pb  = proj_b  + layer * 256;
        const u16*   f1w = fc1_wt  + (size_t)layer * 1024 * 256;
        const float* f1b = fc1_b   + layer * 1024;
        const u16*   f2w = fc2_wt  + (size_t)layer * 256 * 1024;
        const float* f2b = fc2_b   + layer * 256;

        // layer 0 reads the original input directly (skips the 32 MB D2D copy)
        const float* xsrc = (layer == 0) ? x_in : xbuf;

        ln_f2b_kernel<<<8192, 256, 0, stream>>>(xsrc, l1g, l1b, xn);
        {
            const int Mg = nb * 2048;
            u16* qkvc  = S;
            u16* atnoc = S + (size_t)Mg * 768;
            for (int g = 0; g < 16 / nb; ++g) {
                const size_t t0 = (size_t)g * Mg;
                gemm_kernel<0><<<dim3(Mg / 128, 6), 256, 0, stream>>>(
                    xn + t0 * 256, qwt, qb, nullptr, qkvc, Mg, 768, 256);
                attn_kernel<<<Mg / 4, 256, 0, stream>>>(qkvc, atnoc);
                gemm_kernel<1><<<dim3(Mg / 128, 2), 256, 0, stream>>>(
                    atnoc, pwt, pb, xsrc + t0 * 256, xbuf + t0 * 256, Mg, 256, 256);
            }
        }
        ln_f2b_kernel<<<8192, 256, 0, stream>>>(xbuf, l2g, l2b, xn);
        {
            u16* hbuf = S;
            for (int qq = 0; qq < 32768 / Mf; ++qq) {
                const size_t r0 = (size_t)qq * Mf;
                gemm_kernel<2><<<dim3(Mf / 128, 8), 256, 0, stream>>>(
                    xn + r0 * 256, f1w, f1b, nullptr, hbuf, Mf, 1024, 256);
                gemm_kernel<1><<<dim3(Mf / 128, 2), 256, 0, stream>>>(
                    hbuf, f2w, f2b, xbuf + r0 * 256, xbuf + r0 * 256, Mf, 256, 1024);
            }
        }
    }

    // downsample conv (im2col GEMM) + final LN -> fp32 y, chunked
    {
        u16* x2c = S;
        u16* ycc = S + (size_t)Mc * 768;
        for (int c = 0; c < 16384 / Mc; ++c) {
            const int r0 = c * Mc;
            im2col_kernel<<<3 * Mc / 4, 256, 0, stream>>>(xbuf, x2c, r0);
            gemm_kernel<3><<<dim3(Mc / 128, 4), 256, 0, stream>>>(
                x2c, conv_wt, nullptr, nullptr, ycc, Mc, 512, 768);
            ln_b2f_kernel<<<Mc / 4, 256, 0, stream>>>(
                ycc, dn_g, dn_b, (float*)d_out + (size_t)r0 * 512);
        }
    }
    // x output already in place (xbuf aliases d_out's x-region)
}